// Round 1
// baseline (1281.304 us; speedup 1.0000x reference)
//
#include <hip/hip_runtime.h>

// Problem constants (from reference)
constexpr int NUM_SEQS  = 32;
constexpr int KV_LEN    = 2048;
constexpr int NUM_HEADS = 16;
constexpr int HEAD_SIZE = 128;
constexpr float SCALE   = 0.08838834764831845f;

constexpr int HSTRIDE = NUM_HEADS * HEAD_SIZE;                    // floats per slot (2048)
constexpr size_t KV_PLANE = (size_t)NUM_SEQS * KV_LEN * HSTRIDE;  // elements in K plane

// One block per (seq, head). 256 threads = 8 half-waves of 32 lanes.
// Each half-wave processes 4 KV positions per iteration: 32 lanes x float4
// = one position's 128 contiguous floats (perfectly coalesced, 4 loads in
// flight per lane for MLP).
//
// reshape_and_cache is NOT materialized: the graded output only depends on
// the post-scatter cache, and slot_mapping[s] addresses seq s's own range,
// so we substitute k/v at t == slot_mapping[s] - s*KV_LEN on the fly.
__global__ __launch_bounds__(256, 4)
void paged_decode_kernel(const float* __restrict__ q,
                         const float* __restrict__ knew,
                         const float* __restrict__ vnew,
                         const float* __restrict__ kv,
                         const int*  __restrict__ slot_map,
                         float* __restrict__ out)
{
    const int bid  = blockIdx.x;
    const int s    = bid >> 4;              // seq
    const int h    = bid & (NUM_HEADS - 1); // head
    const int tid  = threadIdx.x;
    const int half = tid >> 5;              // 0..7  (half-wave id)
    const int lane = tid & 31;              // lane within half-wave

    __shared__ float sc[KV_LEN];            // scores, then probs (8 KB)
    __shared__ float red[4];                // per-wave reduction scratch
    __shared__ float s_inv;                 // 1/sum
    __shared__ float part[8][HEAD_SIZE];    // per-half partial outputs (4 KB)

    const int qoff = (s * NUM_HEADS + h) * HEAD_SIZE;
    const float* kbase = kv + (size_t)s * KV_LEN * HSTRIDE + (size_t)h * HEAD_SIZE;
    const float* vbase = kbase + KV_PLANE;
    const int t_new = slot_map[s] - s * KV_LEN;   // position replaced by new token

    const float4 qv = *reinterpret_cast<const float4*>(q + qoff + lane * 4);

    // ---------------- Phase 1: scores = (q . k) * SCALE ----------------
    for (int base = 0; base < KV_LEN; base += 32) {
        const int t0 = base + half * 4;

        const float* p0 = (t0 + 0 == t_new) ? (knew + qoff) : (kbase + (size_t)(t0 + 0) * HSTRIDE);
        const float* p1 = (t0 + 1 == t_new) ? (knew + qoff) : (kbase + (size_t)(t0 + 1) * HSTRIDE);
        const float* p2 = (t0 + 2 == t_new) ? (knew + qoff) : (kbase + (size_t)(t0 + 2) * HSTRIDE);
        const float* p3 = (t0 + 3 == t_new) ? (knew + qoff) : (kbase + (size_t)(t0 + 3) * HSTRIDE);

        const float4 k0 = *reinterpret_cast<const float4*>(p0 + lane * 4);
        const float4 k1 = *reinterpret_cast<const float4*>(p1 + lane * 4);
        const float4 k2 = *reinterpret_cast<const float4*>(p2 + lane * 4);
        const float4 k3 = *reinterpret_cast<const float4*>(p3 + lane * 4);

        float d0 = fmaf(k0.x, qv.x, fmaf(k0.y, qv.y, fmaf(k0.z, qv.z, k0.w * qv.w)));
        float d1 = fmaf(k1.x, qv.x, fmaf(k1.y, qv.y, fmaf(k1.z, qv.z, k1.w * qv.w)));
        float d2 = fmaf(k2.x, qv.x, fmaf(k2.y, qv.y, fmaf(k2.z, qv.z, k2.w * qv.w)));
        float d3 = fmaf(k3.x, qv.x, fmaf(k3.y, qv.y, fmaf(k3.z, qv.z, k3.w * qv.w)));

        // 32-lane tree reduce (xor masks <32 never cross the half-wave boundary)
        #pragma unroll
        for (int off = 16; off > 0; off >>= 1) {
            d0 += __shfl_xor(d0, off);
            d1 += __shfl_xor(d1, off);
            d2 += __shfl_xor(d2, off);
            d3 += __shfl_xor(d3, off);
        }
        if (lane == 0) {
            sc[t0 + 0] = d0 * SCALE;
            sc[t0 + 1] = d1 * SCALE;
            sc[t0 + 2] = d2 * SCALE;
            sc[t0 + 3] = d3 * SCALE;
        }
    }
    __syncthreads();

    // ---------------- softmax: max ----------------
    float m = -1e30f;
    #pragma unroll
    for (int t = tid; t < KV_LEN; t += 256) m = fmaxf(m, sc[t]);
    #pragma unroll
    for (int off = 32; off > 0; off >>= 1) m = fmaxf(m, __shfl_xor(m, off));
    if ((tid & 63) == 0) red[tid >> 6] = m;
    __syncthreads();
    const float mblk = fmaxf(fmaxf(red[0], red[1]), fmaxf(red[2], red[3]));

    // ---------------- softmax: exp + sum ----------------
    float lsum = 0.f;
    #pragma unroll
    for (int t = tid; t < KV_LEN; t += 256) {
        const float e = __expf(sc[t] - mblk);
        sc[t] = e;
        lsum += e;
    }
    #pragma unroll
    for (int off = 32; off > 0; off >>= 1) lsum += __shfl_xor(lsum, off);
    __syncthreads();                     // protect red[] reuse
    if ((tid & 63) == 0) red[tid >> 6] = lsum;
    __syncthreads();
    if (tid == 0) s_inv = 1.0f / (red[0] + red[1] + red[2] + red[3]);
    __syncthreads();                     // also publishes sc[] prob values
    const float inv = s_inv;

    // ---------------- Phase 2: out = probs . V ----------------
    float4 acc = make_float4(0.f, 0.f, 0.f, 0.f);
    for (int base = 0; base < KV_LEN; base += 32) {
        const int t0 = base + half * 4;

        const float* p0 = (t0 + 0 == t_new) ? (vnew + qoff) : (vbase + (size_t)(t0 + 0) * HSTRIDE);
        const float* p1 = (t0 + 1 == t_new) ? (vnew + qoff) : (vbase + (size_t)(t0 + 1) * HSTRIDE);
        const float* p2 = (t0 + 2 == t_new) ? (vnew + qoff) : (vbase + (size_t)(t0 + 2) * HSTRIDE);
        const float* p3 = (t0 + 3 == t_new) ? (vnew + qoff) : (vbase + (size_t)(t0 + 3) * HSTRIDE);

        const float4 v0 = *reinterpret_cast<const float4*>(p0 + lane * 4);
        const float4 v1 = *reinterpret_cast<const float4*>(p1 + lane * 4);
        const float4 v2 = *reinterpret_cast<const float4*>(p2 + lane * 4);
        const float4 v3 = *reinterpret_cast<const float4*>(p3 + lane * 4);

        const float w0 = sc[t0 + 0];   // LDS broadcast (same addr across lanes)
        const float w1 = sc[t0 + 1];
        const float w2 = sc[t0 + 2];
        const float w3 = sc[t0 + 3];

        acc.x = fmaf(w0, v0.x, acc.x); acc.y = fmaf(w0, v0.y, acc.y);
        acc.z = fmaf(w0, v0.z, acc.z); acc.w = fmaf(w0, v0.w, acc.w);
        acc.x = fmaf(w1, v1.x, acc.x); acc.y = fmaf(w1, v1.y, acc.y);
        acc.z = fmaf(w1, v1.z, acc.z); acc.w = fmaf(w1, v1.w, acc.w);
        acc.x = fmaf(w2, v2.x, acc.x); acc.y = fmaf(w2, v2.y, acc.y);
        acc.z = fmaf(w2, v2.z, acc.z); acc.w = fmaf(w2, v2.w, acc.w);
        acc.x = fmaf(w3, v3.x, acc.x); acc.y = fmaf(w3, v3.y, acc.y);
        acc.z = fmaf(w3, v3.z, acc.z); acc.w = fmaf(w3, v3.w, acc.w);
    }

    *reinterpret_cast<float4*>(&part[half][lane * 4]) = acc;
    __syncthreads();

    if (tid < HEAD_SIZE) {
        float o = 0.f;
        #pragma unroll
        for (int i = 0; i < 8; ++i) o += part[i][tid];
        out[qoff + tid] = o * inv;
    }
}

extern "C" void kernel_launch(void* const* d_in, const int* in_sizes, int n_in,
                              void* d_out, int out_size, void* d_ws, size_t ws_size,
                              hipStream_t stream) {
    const float* q    = (const float*)d_in[0];
    const float* k    = (const float*)d_in[1];
    const float* v    = (const float*)d_in[2];
    const float* kv   = (const float*)d_in[3];
    const int*   slot = (const int*)d_in[4];
    float* out = (float*)d_out;

    dim3 grid(NUM_SEQS * NUM_HEADS);   // 512 blocks, one per (seq, head)
    dim3 block(256);
    hipLaunchKernelGGL(paged_decode_kernel, grid, block, 0, stream,
                       q, k, v, kv, slot, out);
}